// Round 4
// baseline (773.749 us; speedup 1.0000x reference)
//
#include <hip/hip_runtime.h>
#include <math.h>

#define NN 50000
#define NE 800000
#define DIN 128
#define DH 64
#define NG 64

// ---------------- degree histogram ----------------
__global__ void deg_kernel(const int* __restrict__ col, int* __restrict__ indeg, int e) {
    int i = blockIdx.x * blockDim.x + threadIdx.x;
    int stride = gridDim.x * blockDim.x;
    for (; i < e; i += stride) atomicAdd(&indeg[col[i]], 1);
}

// dinv[i] = rsqrt(indeg[i] + 1)   (+1 = self loop; always > 0)
__global__ void dinv_kernel(const int* __restrict__ indeg, float* __restrict__ dinv, int n) {
    int i = blockIdx.x * blockDim.x + threadIdx.x;
    if (i < n) dinv[i] = rsqrtf((float)(indeg[i] + 1));
}

// ---------------- exclusive scan of indeg -> csr_off (single block, chunked wave scan) ----------------
__global__ __launch_bounds__(1024) void scan_kernel(const int* __restrict__ indeg,
                                                    int* __restrict__ off, int n) {
    __shared__ int wsum[16];
    __shared__ int carry_s;
    int tid = threadIdx.x;
    int lane = tid & 63, wid = tid >> 6;
    if (tid == 0) carry_s = 0;
    __syncthreads();
    for (int base = 0; base < n; base += 1024) {
        int i = base + tid;
        int v0 = (i < n) ? indeg[i] : 0;
        int v = v0;
        #pragma unroll
        for (int d = 1; d < 64; d <<= 1) {
            int t = __shfl_up(v, d, 64);
            if (lane >= d) v += t;
        }
        if (lane == 63) wsum[wid] = v;
        __syncthreads();
        if (wid == 0) {
            int wv = (lane < 16) ? wsum[lane] : 0;
            #pragma unroll
            for (int d = 1; d < 16; d <<= 1) {
                int t = __shfl_up(wv, d, 64);
                if (lane >= d) wv += t;
            }
            if (lane < 16) wsum[lane] = wv;
        }
        __syncthreads();
        int woff = (wid == 0) ? 0 : wsum[wid - 1];
        int carry = carry_s;
        if (i < n) off[i] = carry + woff + (v - v0);   // exclusive
        int total = wsum[15];
        __syncthreads();
        if (tid == 0) carry_s = carry + total;
        __syncthreads();
    }
    if (tid == 0) off[n] = carry_s;
}

__global__ void init_cursor_kernel(const int* __restrict__ off, int* __restrict__ cur, int n) {
    int i = blockIdx.x * blockDim.x + threadIdx.x;
    if (i < n) cur[i] = off[i];
}

// bucket edges by target: ew[p] = { bitcast(src), dinv[src]*dinv[col] }
__global__ void fill_kernel(const int* __restrict__ row, const int* __restrict__ col,
                            const float* __restrict__ dinv, int* __restrict__ cursor,
                            float2* __restrict__ ew, int e) {
    int i = blockIdx.x * blockDim.x + threadIdx.x;
    int stride = gridDim.x * blockDim.x;
    for (; i < e; i += stride) {
        int c = col[i], r = row[i];
        int p = atomicAdd(&cursor[c], 1);
        ew[p] = make_float2(__int_as_float(r), dinv[r] * dinv[c]);
    }
}

// ---------------- GEMM: out[N,64] = in[N,K] @ W[K,64] ----------------
// Register-tiled: block = 256 threads covers 64 nodes; each thread computes a
// 4-node x 4-feature tile. lane = (nl<<4)|fq: fq = feature quad (4*fq..4*fq+3),
// nl = node subgroup. W staged once per block (782 blocks, not 12500) and read
// as ds_read_b128 (fq/fq+8 2-way alias = free; nl groups broadcast).
// Round-3 version was 1 output/thread -> 128 ds_read_b32 per output, LDS-issue
// bound at 70us / 26% VALUBusy.
template <int K>
__global__ __launch_bounds__(256) void gemm_kernel(const float* __restrict__ in,
                                                   const float* __restrict__ W,
                                                   float* __restrict__ out, int n) {
    __shared__ float Ws[K * 64];
    for (int t = threadIdx.x; t < K * 16; t += 256)
        reinterpret_cast<float4*>(Ws)[t] = reinterpret_cast<const float4*>(W)[t];
    __syncthreads();

    int w = threadIdx.x >> 6, l = threadIdx.x & 63;
    int fq = l & 15;    // features 4*fq .. 4*fq+3
    int nl = l >> 4;    // node subgroup within wave
    int base = blockIdx.x * 64 + w * 16 + nl * 4;

    // clamped row pointers (safe OOB reads; stores are guarded)
    const float* r0 = in + (size_t)min(base + 0, n - 1) * K;
    const float* r1 = in + (size_t)min(base + 1, n - 1) * K;
    const float* r2 = in + (size_t)min(base + 2, n - 1) * K;
    const float* r3 = in + (size_t)min(base + 3, n - 1) * K;

    float acc[4][4];
    #pragma unroll
    for (int i = 0; i < 4; ++i)
        #pragma unroll
        for (int f = 0; f < 4; ++f) acc[i][f] = 0.f;

    #pragma unroll
    for (int k = 0; k < K; k += 4) {
        float4 wv[4];
        #pragma unroll
        for (int kk = 0; kk < 4; ++kk)
            wv[kk] = *reinterpret_cast<const float4*>(&Ws[(k + kk) * 64 + 4 * fq]);
        float4 xv[4];
        xv[0] = *reinterpret_cast<const float4*>(r0 + k);
        xv[1] = *reinterpret_cast<const float4*>(r1 + k);
        xv[2] = *reinterpret_cast<const float4*>(r2 + k);
        xv[3] = *reinterpret_cast<const float4*>(r3 + k);
        #pragma unroll
        for (int i = 0; i < 4; ++i) {
            float xs[4] = {xv[i].x, xv[i].y, xv[i].z, xv[i].w};
            #pragma unroll
            for (int kk = 0; kk < 4; ++kk) {
                acc[i][0] = fmaf(xs[kk], wv[kk].x, acc[i][0]);
                acc[i][1] = fmaf(xs[kk], wv[kk].y, acc[i][1]);
                acc[i][2] = fmaf(xs[kk], wv[kk].z, acc[i][2]);
                acc[i][3] = fmaf(xs[kk], wv[kk].w, acc[i][3]);
            }
        }
    }

    #pragma unroll
    for (int i = 0; i < 4; ++i) {
        int node = base + i;
        if (node < n) {
            float4 o = make_float4(acc[i][0], acc[i][1], acc[i][2], acc[i][3]);
            *reinterpret_cast<float4*>(&out[(size_t)node * 64 + 4 * fq]) = o;
        }
    }
}

// ---------------- pull aggregation + bias + ELU: one wave per node, lane = feature ----------------
__global__ __launch_bounds__(256) void pull_kernel(const float* __restrict__ tmp,
                                                   const int* __restrict__ off,
                                                   const float2* __restrict__ ew,
                                                   const float* __restrict__ dinv,
                                                   const float* __restrict__ bias,
                                                   float* __restrict__ out, int n) {
    int wid = threadIdx.x >> 6;
    int lane = threadIdx.x & 63;
    int node = blockIdx.x * 4 + wid;
    if (node >= n) return;
    float dt = dinv[node];
    float acc = tmp[(size_t)node * 64 + lane] * dt * dt;   // self loop
    int e = off[node], s1 = off[node + 1];
    for (; e + 4 <= s1; e += 4) {
        float2 m0 = ew[e + 0];
        float2 m1 = ew[e + 1];
        float2 m2 = ew[e + 2];
        float2 m3 = ew[e + 3];
        float v0 = tmp[(size_t)__float_as_int(m0.x) * 64 + lane];
        float v1 = tmp[(size_t)__float_as_int(m1.x) * 64 + lane];
        float v2 = tmp[(size_t)__float_as_int(m2.x) * 64 + lane];
        float v3 = tmp[(size_t)__float_as_int(m3.x) * 64 + lane];
        acc = fmaf(v0, m0.y, acc);
        acc = fmaf(v1, m1.y, acc);
        acc = fmaf(v2, m2.y, acc);
        acc = fmaf(v3, m3.y, acc);
    }
    for (; e < s1; ++e) {
        float2 m = ew[e];
        acc = fmaf(tmp[(size_t)__float_as_int(m.x) * 64 + lane], m.y, acc);
    }
    float v = acc + bias[lane];
    out[(size_t)node * 64 + lane] = (v > 0.f) ? v : expm1f(v);
}

// ---------------- final linear + grouped mean-pool partials ----------------
#define POOL_BLOCKS 256
__global__ __launch_bounds__(256) void final_pool_kernel(const float* __restrict__ h,
                                                         const float* __restrict__ Wl,
                                                         const int* __restrict__ batch,
                                                         float* __restrict__ gsum,
                                                         float* __restrict__ gcnt, int n) {
    __shared__ float lsum[NG];
    __shared__ float lcnt[NG];
    if (threadIdx.x < NG) { lsum[threadIdx.x] = 0.f; lcnt[threadIdx.x] = 0.f; }
    __syncthreads();
    int wid = threadIdx.x >> 6, lane = threadIdx.x & 63;
    float wl = Wl[lane];
    int per_block = (n + POOL_BLOCKS - 1) / POOL_BLOCKS;
    int start = blockIdx.x * per_block;
    int end = start + per_block;
    if (end > n) end = n;
    for (int node = start + wid; node < end; node += 4) {
        float p = h[(size_t)node * 64 + lane] * wl;
        #pragma unroll
        for (int d = 32; d >= 1; d >>= 1) p += __shfl_xor(p, d, 64);
        if (lane == 0) {
            int g = batch[node];
            atomicAdd(&lsum[g], p);
            atomicAdd(&lcnt[g], 1.f);
        }
    }
    __syncthreads();
    if (threadIdx.x < NG && lcnt[threadIdx.x] != 0.f) {
        atomicAdd(&gsum[threadIdx.x], lsum[threadIdx.x]);
        atomicAdd(&gcnt[threadIdx.x], lcnt[threadIdx.x]);
    }
}

__global__ void pool_div_kernel(const float* __restrict__ gsum, const float* __restrict__ gcnt,
                                const float* __restrict__ bl, float* __restrict__ out) {
    int g = threadIdx.x;
    if (g < NG) {
        float c = gcnt[g];
        out[g] = (c > 0.5f) ? (gsum[g] / c + bl[0]) : 0.f;
    }
}

extern "C" void kernel_launch(void* const* d_in, const int* in_sizes, int n_in,
                              void* d_out, int out_size, void* d_ws, size_t ws_size,
                              hipStream_t stream) {
    const float* x    = (const float*)d_in[0];
    const int*   eidx = (const int*)d_in[1];
    const int*   row  = eidx;              // edge_index[0] = sources
    const int*   col  = eidx + NE;         // edge_index[1] = targets
    const int*   batch = (const int*)d_in[2];
    const float* W1 = (const float*)d_in[3];
    const float* b1 = (const float*)d_in[4];
    const float* W2 = (const float*)d_in[5];
    const float* b2 = (const float*)d_in[6];
    const float* W3 = (const float*)d_in[7];
    const float* b3 = (const float*)d_in[8];
    const float* Wl = (const float*)d_in[9];
    const float* bl = (const float*)d_in[10];
    float* out = (float*)d_out;

    // workspace layout (all offsets 64-element = 256B aligned)
    size_t cur = 0;
    auto take = [&](size_t elems) { size_t c = cur; cur += (elems + 63) & ~(size_t)63; return c; };
    float* base_f = (float*)d_ws;
    int*   base_i = (int*)d_ws;

    float*  dinv    = base_f + take(NN);
    int*    indeg   = base_i + take(NN);
    int*    csr_off = base_i + take(NN + 1);
    int*    cursor  = base_i + take(NN);
    float2* ew      = (float2*)(base_f + take((size_t)NE * 2));
    float*  tmp     = base_f + take((size_t)NN * 64);
    float*  h       = base_f + take((size_t)NN * 64);
    float*  gsum    = base_f + take(NG);
    float*  gcnt    = base_f + take(NG);
    (void)ws_size; (void)n_in; (void)in_sizes; (void)out_size;

    // ---- CSR build ----
    hipMemsetAsync(indeg, 0, NN * sizeof(int), stream);
    hipMemsetAsync(gsum, 0, NG * sizeof(float), stream);
    hipMemsetAsync(gcnt, 0, NG * sizeof(float), stream);

    deg_kernel<<<1024, 256, 0, stream>>>(col, indeg, NE);
    dinv_kernel<<<(NN + 255) / 256, 256, 0, stream>>>(indeg, dinv, NN);
    scan_kernel<<<1, 1024, 0, stream>>>(indeg, csr_off, NN);
    init_cursor_kernel<<<(NN + 255) / 256, 256, 0, stream>>>(csr_off, cursor, NN);
    fill_kernel<<<1024, 256, 0, stream>>>(row, col, dinv, cursor, ew, NE);

    const int nblk_pull = (NN + 3) / 4;    // 4 nodes / 256-thread block (pull)
    const int nblk_gemm = (NN + 63) / 64;  // 64 nodes / 256-thread block (gemm)

    // ---- layer 1: tmp = x @ W1 ; h = elu(pull(tmp) + b1) ----
    gemm_kernel<DIN><<<nblk_gemm, 256, 0, stream>>>(x, W1, tmp, NN);
    pull_kernel<<<nblk_pull, 256, 0, stream>>>(tmp, csr_off, ew, dinv, b1, h, NN);

    // ---- layer 2 ----
    gemm_kernel<DH><<<nblk_gemm, 256, 0, stream>>>(h, W2, tmp, NN);
    pull_kernel<<<nblk_pull, 256, 0, stream>>>(tmp, csr_off, ew, dinv, b2, h, NN);

    // ---- layer 3 ----
    gemm_kernel<DH><<<nblk_gemm, 256, 0, stream>>>(h, W3, tmp, NN);
    pull_kernel<<<nblk_pull, 256, 0, stream>>>(tmp, csr_off, ew, dinv, b3, h, NN);

    // ---- final linear + mean pool ----
    final_pool_kernel<<<POOL_BLOCKS, 256, 0, stream>>>(h, Wl, batch, gsum, gcnt, NN);
    pool_div_kernel<<<1, 64, 0, stream>>>(gsum, gcnt, bl, out);
}

// Round 5
// 415.622 us; speedup vs baseline: 1.8617x; 1.8617x over previous
//
#include <hip/hip_runtime.h>
#include <math.h>

#define NN 50000
#define NE 800000
#define DIN 128
#define DH 64
#define NG 64

// ---------------- degree histogram ----------------
__global__ void deg_kernel(const int* __restrict__ col, int* __restrict__ indeg, int e) {
    int i = blockIdx.x * blockDim.x + threadIdx.x;
    int stride = gridDim.x * blockDim.x;
    for (; i < e; i += stride) atomicAdd(&indeg[col[i]], 1);
}

// dinv[i] = rsqrt(indeg[i] + 1)   (+1 = self loop; always > 0)
__global__ void dinv_kernel(const int* __restrict__ indeg, float* __restrict__ dinv, int n) {
    int i = blockIdx.x * blockDim.x + threadIdx.x;
    if (i < n) dinv[i] = rsqrtf((float)(indeg[i] + 1));
}

// ---------------- exclusive scan of indeg -> csr_off (single block, chunked wave scan) ----------------
__global__ __launch_bounds__(1024) void scan_kernel(const int* __restrict__ indeg,
                                                    int* __restrict__ off, int n) {
    __shared__ int wsum[16];
    __shared__ int carry_s;
    int tid = threadIdx.x;
    int lane = tid & 63, wid = tid >> 6;
    if (tid == 0) carry_s = 0;
    __syncthreads();
    for (int base = 0; base < n; base += 1024) {
        int i = base + tid;
        int v0 = (i < n) ? indeg[i] : 0;
        int v = v0;
        #pragma unroll
        for (int d = 1; d < 64; d <<= 1) {
            int t = __shfl_up(v, d, 64);
            if (lane >= d) v += t;
        }
        if (lane == 63) wsum[wid] = v;
        __syncthreads();
        if (wid == 0) {
            int wv = (lane < 16) ? wsum[lane] : 0;
            #pragma unroll
            for (int d = 1; d < 16; d <<= 1) {
                int t = __shfl_up(wv, d, 64);
                if (lane >= d) wv += t;
            }
            if (lane < 16) wsum[lane] = wv;
        }
        __syncthreads();
        int woff = (wid == 0) ? 0 : wsum[wid - 1];
        int carry = carry_s;
        if (i < n) off[i] = carry + woff + (v - v0);   // exclusive
        int total = wsum[15];
        __syncthreads();
        if (tid == 0) carry_s = carry + total;
        __syncthreads();
    }
    if (tid == 0) off[n] = carry_s;
}

__global__ void init_cursor_kernel(const int* __restrict__ off, int* __restrict__ cur, int n) {
    int i = blockIdx.x * blockDim.x + threadIdx.x;
    if (i < n) cur[i] = off[i];
}

// bucket edges by target: ew[p] = { bitcast(src), dinv[src]*dinv[col] }
__global__ void fill_kernel(const int* __restrict__ row, const int* __restrict__ col,
                            const float* __restrict__ dinv, int* __restrict__ cursor,
                            float2* __restrict__ ew, int e) {
    int i = blockIdx.x * blockDim.x + threadIdx.x;
    int stride = gridDim.x * blockDim.x;
    for (; i < e; i += stride) {
        int c = col[i], r = row[i];
        int p = atomicAdd(&cursor[c], 1);
        ew[p] = make_float2(__int_as_float(r), dinv[r] * dinv[c]);
    }
}

// ---------------- GEMM: out[N,64] = in[N,K] @ W[K,64] ----------------
// Register-tiled: 256 threads cover 64 nodes; each thread computes a 4-node x
// 4-feature tile. Round-4 lesson: FULL unroll of the K loop let the scheduler
// hoist all wv/xv loads -> 256 VGPR + scratch spills (428MB fetch, 447us).
// Fix: unroll 2 only (body already has 4-wide k-step ILP), and
// __launch_bounds__(256,4) caps the allocator at 128 VGPR (4 waves/SIMD).
template <int K>
__global__ __launch_bounds__(256, 4) void gemm_kernel(const float* __restrict__ in,
                                                      const float* __restrict__ W,
                                                      float* __restrict__ out, int n) {
    __shared__ float Ws[K * 64];
    for (int t = threadIdx.x; t < K * 16; t += 256)
        reinterpret_cast<float4*>(Ws)[t] = reinterpret_cast<const float4*>(W)[t];
    __syncthreads();

    int w = threadIdx.x >> 6, l = threadIdx.x & 63;
    int fq = l & 15;    // features 4*fq .. 4*fq+3
    int nl = l >> 4;    // node subgroup within wave
    int base = blockIdx.x * 64 + w * 16 + nl * 4;

    // clamped row pointers (safe OOB reads; stores are guarded)
    const float* r0 = in + (size_t)min(base + 0, n - 1) * K;
    const float* r1 = in + (size_t)min(base + 1, n - 1) * K;
    const float* r2 = in + (size_t)min(base + 2, n - 1) * K;
    const float* r3 = in + (size_t)min(base + 3, n - 1) * K;

    float acc[4][4];
    #pragma unroll
    for (int i = 0; i < 4; ++i)
        #pragma unroll
        for (int f = 0; f < 4; ++f) acc[i][f] = 0.f;

    #pragma unroll 2
    for (int k = 0; k < K; k += 4) {
        float4 wv[4];
        #pragma unroll
        for (int kk = 0; kk < 4; ++kk)
            wv[kk] = *reinterpret_cast<const float4*>(&Ws[(k + kk) * 64 + 4 * fq]);
        float4 xv[4];
        xv[0] = *reinterpret_cast<const float4*>(r0 + k);
        xv[1] = *reinterpret_cast<const float4*>(r1 + k);
        xv[2] = *reinterpret_cast<const float4*>(r2 + k);
        xv[3] = *reinterpret_cast<const float4*>(r3 + k);
        #pragma unroll
        for (int i = 0; i < 4; ++i) {
            float xs[4] = {xv[i].x, xv[i].y, xv[i].z, xv[i].w};
            #pragma unroll
            for (int kk = 0; kk < 4; ++kk) {
                acc[i][0] = fmaf(xs[kk], wv[kk].x, acc[i][0]);
                acc[i][1] = fmaf(xs[kk], wv[kk].y, acc[i][1]);
                acc[i][2] = fmaf(xs[kk], wv[kk].z, acc[i][2]);
                acc[i][3] = fmaf(xs[kk], wv[kk].w, acc[i][3]);
            }
        }
    }

    #pragma unroll
    for (int i = 0; i < 4; ++i) {
        int node = base + i;
        if (node < n) {
            float4 o = make_float4(acc[i][0], acc[i][1], acc[i][2], acc[i][3]);
            *reinterpret_cast<float4*>(&out[(size_t)node * 64 + 4 * fq]) = o;
        }
    }
}

// ---------------- pull aggregation + bias + ELU: one wave per node, lane = feature ----------------
__global__ __launch_bounds__(256) void pull_kernel(const float* __restrict__ tmp,
                                                   const int* __restrict__ off,
                                                   const float2* __restrict__ ew,
                                                   const float* __restrict__ dinv,
                                                   const float* __restrict__ bias,
                                                   float* __restrict__ out, int n) {
    int wid = threadIdx.x >> 6;
    int lane = threadIdx.x & 63;
    int node = blockIdx.x * 4 + wid;
    if (node >= n) return;
    float dt = dinv[node];
    float acc = tmp[(size_t)node * 64 + lane] * dt * dt;   // self loop
    int e = off[node], s1 = off[node + 1];
    for (; e + 4 <= s1; e += 4) {
        float2 m0 = ew[e + 0];
        float2 m1 = ew[e + 1];
        float2 m2 = ew[e + 2];
        float2 m3 = ew[e + 3];
        float v0 = tmp[(size_t)__float_as_int(m0.x) * 64 + lane];
        float v1 = tmp[(size_t)__float_as_int(m1.x) * 64 + lane];
        float v2 = tmp[(size_t)__float_as_int(m2.x) * 64 + lane];
        float v3 = tmp[(size_t)__float_as_int(m3.x) * 64 + lane];
        acc = fmaf(v0, m0.y, acc);
        acc = fmaf(v1, m1.y, acc);
        acc = fmaf(v2, m2.y, acc);
        acc = fmaf(v3, m3.y, acc);
    }
    for (; e < s1; ++e) {
        float2 m = ew[e];
        acc = fmaf(tmp[(size_t)__float_as_int(m.x) * 64 + lane], m.y, acc);
    }
    float v = acc + bias[lane];
    out[(size_t)node * 64 + lane] = (v > 0.f) ? v : expm1f(v);
}

// ---------------- final linear + grouped mean-pool partials ----------------
#define POOL_BLOCKS 256
__global__ __launch_bounds__(256) void final_pool_kernel(const float* __restrict__ h,
                                                         const float* __restrict__ Wl,
                                                         const int* __restrict__ batch,
                                                         float* __restrict__ gsum,
                                                         float* __restrict__ gcnt, int n) {
    __shared__ float lsum[NG];
    __shared__ float lcnt[NG];
    if (threadIdx.x < NG) { lsum[threadIdx.x] = 0.f; lcnt[threadIdx.x] = 0.f; }
    __syncthreads();
    int wid = threadIdx.x >> 6, lane = threadIdx.x & 63;
    float wl = Wl[lane];
    int per_block = (n + POOL_BLOCKS - 1) / POOL_BLOCKS;
    int start = blockIdx.x * per_block;
    int end = start + per_block;
    if (end > n) end = n;
    for (int node = start + wid; node < end; node += 4) {
        float p = h[(size_t)node * 64 + lane] * wl;
        #pragma unroll
        for (int d = 32; d >= 1; d >>= 1) p += __shfl_xor(p, d, 64);
        if (lane == 0) {
            int g = batch[node];
            atomicAdd(&lsum[g], p);
            atomicAdd(&lcnt[g], 1.f);
        }
    }
    __syncthreads();
    if (threadIdx.x < NG && lcnt[threadIdx.x] != 0.f) {
        atomicAdd(&gsum[threadIdx.x], lsum[threadIdx.x]);
        atomicAdd(&gcnt[threadIdx.x], lcnt[threadIdx.x]);
    }
}

__global__ void pool_div_kernel(const float* __restrict__ gsum, const float* __restrict__ gcnt,
                                const float* __restrict__ bl, float* __restrict__ out) {
    int g = threadIdx.x;
    if (g < NG) {
        float c = gcnt[g];
        out[g] = (c > 0.5f) ? (gsum[g] / c + bl[0]) : 0.f;
    }
}

extern "C" void kernel_launch(void* const* d_in, const int* in_sizes, int n_in,
                              void* d_out, int out_size, void* d_ws, size_t ws_size,
                              hipStream_t stream) {
    const float* x    = (const float*)d_in[0];
    const int*   eidx = (const int*)d_in[1];
    const int*   row  = eidx;              // edge_index[0] = sources
    const int*   col  = eidx + NE;         // edge_index[1] = targets
    const int*   batch = (const int*)d_in[2];
    const float* W1 = (const float*)d_in[3];
    const float* b1 = (const float*)d_in[4];
    const float* W2 = (const float*)d_in[5];
    const float* b2 = (const float*)d_in[6];
    const float* W3 = (const float*)d_in[7];
    const float* b3 = (const float*)d_in[8];
    const float* Wl = (const float*)d_in[9];
    const float* bl = (const float*)d_in[10];
    float* out = (float*)d_out;

    // workspace layout (all offsets 64-element = 256B aligned)
    size_t cur = 0;
    auto take = [&](size_t elems) { size_t c = cur; cur += (elems + 63) & ~(size_t)63; return c; };
    float* base_f = (float*)d_ws;
    int*   base_i = (int*)d_ws;

    float*  dinv    = base_f + take(NN);
    int*    indeg   = base_i + take(NN);
    int*    csr_off = base_i + take(NN + 1);
    int*    cursor  = base_i + take(NN);
    float2* ew      = (float2*)(base_f + take((size_t)NE * 2));
    float*  tmp     = base_f + take((size_t)NN * 64);
    float*  h       = base_f + take((size_t)NN * 64);
    float*  gsum    = base_f + take(NG);
    float*  gcnt    = base_f + take(NG);
    (void)ws_size; (void)n_in; (void)in_sizes; (void)out_size;

    // ---- CSR build ----
    hipMemsetAsync(indeg, 0, NN * sizeof(int), stream);
    hipMemsetAsync(gsum, 0, NG * sizeof(float), stream);
    hipMemsetAsync(gcnt, 0, NG * sizeof(float), stream);

    deg_kernel<<<1024, 256, 0, stream>>>(col, indeg, NE);
    dinv_kernel<<<(NN + 255) / 256, 256, 0, stream>>>(indeg, dinv, NN);
    scan_kernel<<<1, 1024, 0, stream>>>(indeg, csr_off, NN);
    init_cursor_kernel<<<(NN + 255) / 256, 256, 0, stream>>>(csr_off, cursor, NN);
    fill_kernel<<<1024, 256, 0, stream>>>(row, col, dinv, cursor, ew, NE);

    const int nblk_pull = (NN + 3) / 4;    // 4 nodes / 256-thread block (pull)
    const int nblk_gemm = (NN + 63) / 64;  // 64 nodes / 256-thread block (gemm)

    // ---- layer 1: tmp = x @ W1 ; h = elu(pull(tmp) + b1) ----
    gemm_kernel<DIN><<<nblk_gemm, 256, 0, stream>>>(x, W1, tmp, NN);
    pull_kernel<<<nblk_pull, 256, 0, stream>>>(tmp, csr_off, ew, dinv, b1, h, NN);

    // ---- layer 2 ----
    gemm_kernel<DH><<<nblk_gemm, 256, 0, stream>>>(h, W2, tmp, NN);
    pull_kernel<<<nblk_pull, 256, 0, stream>>>(tmp, csr_off, ew, dinv, b2, h, NN);

    // ---- layer 3 ----
    gemm_kernel<DH><<<nblk_gemm, 256, 0, stream>>>(h, W3, tmp, NN);
    pull_kernel<<<nblk_pull, 256, 0, stream>>>(tmp, csr_off, ew, dinv, b3, h, NN);

    // ---- final linear + mean pool ----
    final_pool_kernel<<<POOL_BLOCKS, 256, 0, stream>>>(h, Wl, batch, gsum, gcnt, NN);
    pool_div_kernel<<<1, 64, 0, stream>>>(gsum, gcnt, bl, out);
}